// Round 1
// baseline (1148.582 us; speedup 1.0000x reference)
//
#include <hip/hip_runtime.h>
#include <math.h>

// ---------------------------------------------------------------------------
// B=256 images, each layer tokenizes to N=256 tokens (16x16 after unshuffle).
// Layer1: Cu=12, d=16 (dh=4), local r=16, out 64 ch.
// Layer2: Cu=64, d=32 (dh=8), local r=32, out 128 ch.
// pixel_shuffle(L1) o pixel_unshuffle(L2) == identity => t2 = out1 directly.
// fc1: [256,32768]@[32768,1024] (17.2 GF, the hotspot), fc2: [256,1024]@[1024,10].
// All fp32 this round; top-k selection tie-breaks to lowest index like lax.top_k.
// ---------------------------------------------------------------------------

// ---- workspace layout (float offsets); regions reused, peak ~63 MB ----
static constexpr size_t OQ1 = 0;          // 1048576  [B,256,16]
static constexpr size_t OK1 = 1048576;    // 1048576
static constexpr size_t OV1 = 2097152;    // 1048576
static constexpr size_t OL1 = 3145728;    // 1048576
static constexpr size_t OA1 = 4194304;    // 1048576
static constexpr size_t OT2 = 5242880;    // 4194304  [B,256,64], ends 9437184
static constexpr size_t OQ2 = 0;          // 2097152  (q1/k1 dead after attn1)
static constexpr size_t OK2 = 2097152;    // 2097152  (v1/loc1 dead after out1)
static constexpr size_t OV2 = 9437184;    // 2097152
static constexpr size_t OL2 = 11534336;   // 2097152
static constexpr size_t OA2 = 13631488;   // 2097152, ends 15728640 (peak)
static constexpr size_t OH  = 0;          // 8388608  [B,32768] (q2/k2 dead)
static constexpr size_t OPART = 8388608;  // 16*262144 partials, ends 12582912
static constexpr size_t OHFC  = 12582912; // 262144   [256,1024]

// ---------------- K1: pixel_unshuffle + q/k/v/local projections, layer 1 ----
__global__ __launch_bounds__(256) void k1_qkv1(
    const float* __restrict__ x, const float* __restrict__ w1q,
    const float* __restrict__ w1k, const float* __restrict__ w1v,
    const float* __restrict__ w1c, const float* __restrict__ b1c,
    float* __restrict__ q1, float* __restrict__ k1,
    float* __restrict__ v1, float* __restrict__ loc1)
{
  const int tid = threadIdx.x;
  const int slot = tid >> 6;
  const int lane = tid & 63;
  const int tok = blockIdx.x * 4 + slot;   // b*256+n
  const int b = tok >> 8, n = tok & 255;
  const int i = n >> 4, j = n & 15;
  __shared__ float ts[4][12];
  if (lane < 12) {
    const int c0 = lane >> 2, si = (lane >> 1) & 1, sj = lane & 1;
    ts[slot][lane] = x[((size_t)(b * 3 + c0) * 32 + 2 * i + si) * 32 + 2 * j + sj];
  }
  __syncthreads();
  const int mat = lane >> 4, col = lane & 15;
  const float* W = (mat == 0) ? w1q : (mat == 1) ? w1k : (mat == 2) ? w1v : w1c;
  float acc = 0.f;
#pragma unroll
  for (int c = 0; c < 12; ++c) acc += ts[slot][c] * W[c * 16 + col];
  const size_t o = (size_t)tok * 16 + col;
  if (mat == 0) q1[o] = acc;
  else if (mat == 1) k1[o] = acc;
  else if (mat == 2) v1[o] = acc;
  else loc1[o] = fmaxf(acc + b1c[col], 0.f);
}

// ---------------- attention: sim row + top-9 (tie->lowest idx) + softmax + agg
template <int D, int DH>
__global__ __launch_bounds__(256) void attn_kernel(
    const float* __restrict__ q, const float* __restrict__ k,
    const float* __restrict__ v, float* __restrict__ agg)
{
  const int tok = blockIdx.x;        // b*256+n
  const int b = tok >> 8;
  const int t = threadIdx.x;
  __shared__ float qs[D];
  __shared__ float simbuf[256];
  __shared__ int sel[9];
  __shared__ float wt[36];
  if (t < D) qs[t] = q[(size_t)tok * D + t];
  __syncthreads();
  {  // one candidate token per thread
    const float* krow = k + ((size_t)(b << 8) + t) * D;
    float s = 0.f;
#pragma unroll
    for (int c = 0; c < D; ++c) s += qs[c] * krow[c];
    simbuf[t] = s;
  }
  __syncthreads();
  if (t < 64) {  // wave 0 does 9 argmax rounds, shuffle butterfly, no barriers
    float vv[4];
#pragma unroll
    for (int s4 = 0; s4 < 4; ++s4) vv[s4] = simbuf[s4 * 64 + t];
    for (int r = 0; r < 9; ++r) {
      float bv = vv[0]; int bi = t;
#pragma unroll
      for (int s4 = 1; s4 < 4; ++s4)
        if (vv[s4] > bv) { bv = vv[s4]; bi = s4 * 64 + t; }
#pragma unroll
      for (int m = 1; m < 64; m <<= 1) {
        const float ov = __shfl_xor(bv, m, 64);
        const int   oi = __shfl_xor(bi, m, 64);
        if (ov > bv || (ov == bv && oi < bi)) { bv = ov; bi = oi; }
      }
      if (t == 0) sel[r] = bi;
      if ((bi & 63) == t) vv[bi >> 6] = -__builtin_inff();
    }
  }
  __syncthreads();
  if (t < 36) {  // per-head logits: h = t/9, kk = t%9
    const int hh = t / 9, kk = t - hh * 9;
    const float* krow = k + ((size_t)(b << 8) + sel[kk]) * D + hh * DH;
    float s = 0.f;
#pragma unroll
    for (int c = 0; c < DH; ++c) s += qs[hh * DH + c] * krow[c];
    wt[t] = s * (float)(1.0 / sqrt((double)DH));
  }
  __syncthreads();
  if (t < 4) {  // per-head softmax over 9
    float mx = wt[t * 9];
#pragma unroll
    for (int kk = 1; kk < 9; ++kk) mx = fmaxf(mx, wt[t * 9 + kk]);
    float e[9]; float sum = 0.f;
#pragma unroll
    for (int kk = 0; kk < 9; ++kk) { e[kk] = expf(wt[t * 9 + kk] - mx); sum += e[kk]; }
#pragma unroll
    for (int kk = 0; kk < 9; ++kk) wt[t * 9 + kk] = e[kk] / sum;
  }
  __syncthreads();
  if (t < D) {  // aggregate: h = t/DH, c = t%DH
    const int hh = t / DH, c = t - hh * DH;
    float s = 0.f;
#pragma unroll
    for (int kk = 0; kk < 9; ++kk)
      s += wt[hh * 9 + kk] * v[((size_t)(b << 8) + sel[kk]) * D + hh * DH + c];
    agg[(size_t)tok * D + t] = s;
  }
}

// ---------------- K3: concat(local,agg) @ W1o + b1o -> t2 [B,256,64] --------
__global__ __launch_bounds__(256) void k3_out1(
    const float* __restrict__ loc1, const float* __restrict__ agg1,
    const float* __restrict__ w1o, const float* __restrict__ b1o,
    float* __restrict__ t2)
{
  const int tid = threadIdx.x;
  const int slot = tid >> 6, col = tid & 63;
  const int tok = blockIdx.x * 4 + slot;
  __shared__ float cat[4][32];
  if (col < 16) {
    cat[slot][col] = loc1[(size_t)tok * 16 + col];
    cat[slot][col + 16] = agg1[(size_t)tok * 16 + col];
  }
  __syncthreads();
  float acc = b1o[col];
#pragma unroll
  for (int c = 0; c < 32; ++c) acc += cat[slot][c] * w1o[c * 64 + col];
  t2[(size_t)tok * 64 + col] = acc;
}

// ---------------- K4: q/k/v/local projections, layer 2 ----------------------
__global__ __launch_bounds__(256) void k4_qkv2(
    const float* __restrict__ t2, const float* __restrict__ w2q,
    const float* __restrict__ w2k, const float* __restrict__ w2v,
    const float* __restrict__ w2c, const float* __restrict__ b2c,
    float* __restrict__ q2, float* __restrict__ k2,
    float* __restrict__ v2, float* __restrict__ loc2)
{
  const int tid = threadIdx.x;
  const int slot = tid >> 7, r = tid & 127;
  const int tok = blockIdx.x * 2 + slot;
  __shared__ float ts[2][64];
  if (r < 64) ts[slot][r] = t2[(size_t)tok * 64 + r];
  __syncthreads();
  const int mat = r >> 5, col = r & 31;
  const float* W = (mat == 0) ? w2q : (mat == 1) ? w2k : (mat == 2) ? w2v : w2c;
  float acc = 0.f;
#pragma unroll
  for (int c = 0; c < 64; ++c) acc += ts[slot][c] * W[c * 32 + col];
  const size_t o = (size_t)tok * 32 + col;
  if (mat == 0) q2[o] = acc;
  else if (mat == 1) k2[o] = acc;
  else if (mat == 2) v2[o] = acc;
  else loc2[o] = fmaxf(acc + b2c[col], 0.f);
}

// ---------------- K6: out-proj layer2 + pixel_shuffle scatter into h --------
__global__ __launch_bounds__(256) void k6_out2(
    const float* __restrict__ loc2, const float* __restrict__ agg2,
    const float* __restrict__ w2o, const float* __restrict__ b2o,
    float* __restrict__ h)
{
  const int tid = threadIdx.x;
  const int slot = tid >> 7, ch = tid & 127;
  const int tok = blockIdx.x * 2 + slot;
  const int b = tok >> 8, n = tok & 255;
  __shared__ float cat[2][64];
  if (ch < 32) {
    cat[slot][ch] = loc2[(size_t)tok * 32 + ch];
    cat[slot][ch + 32] = agg2[(size_t)tok * 32 + ch];
  }
  __syncthreads();
  float acc = b2o[ch];
#pragma unroll
  for (int c = 0; c < 64; ++c) acc += cat[slot][c] * w2o[c * 128 + ch];
  const int i = n >> 4, j = n & 15;
  const int cc = ch >> 2, si = (ch >> 1) & 1, sj = ch & 1;
  h[(size_t)b * 32768 + cc * 1024 + (2 * i + si) * 32 + (2 * j + sj)] = acc;
}

// ---------------- K7: fc1 GEMM fp32, 64x64 tile, 4x4 microtile, split-K=16 --
__global__ __launch_bounds__(256) void k7_fc1_gemm(
    const float* __restrict__ A,   // h [256, 32768]
    const float* __restrict__ Bw,  // fc1_w [32768, 1024]
    float* __restrict__ part)      // [16][256][1024]
{
  const int bid = blockIdx.x;
  const int bm = bid & 3;          // 4 M-tiles
  const int bn = (bid >> 2) & 15;  // 16 N-tiles
  const int bk = bid >> 6;         // 16 K-chunks of 2048
  const int m0 = bm * 64, n0 = bn * 64, k0 = bk * 2048;
  __shared__ float As[32][68];     // As[kk][r], pad 68 keeps float4 aligned
  __shared__ float Bs[32][64];
  const int tid = threadIdx.x;
  const int r0 = (tid >> 4) * 4;
  const int c0 = (tid & 15) * 4;
  const int ar = tid >> 3;         // 0..31
  const int ak4 = (tid & 7) * 4;   // 0..28
  const int bro = tid >> 4;        // 0..15
  const int bc4 = (tid & 15) * 4;  // 0..60
  float acc[4][4];
#pragma unroll
  for (int i = 0; i < 4; ++i)
#pragma unroll
    for (int jj = 0; jj < 4; ++jj) acc[i][jj] = 0.f;

  for (int kb = k0; kb < k0 + 2048; kb += 32) {
    const float4 a1 = *(const float4*)(A + (size_t)(m0 + ar) * 32768 + kb + ak4);
    const float4 a2 = *(const float4*)(A + (size_t)(m0 + ar + 32) * 32768 + kb + ak4);
    const float4 b1 = *(const float4*)(Bw + (size_t)(kb + bro) * 1024 + n0 + bc4);
    const float4 b2 = *(const float4*)(Bw + (size_t)(kb + bro + 16) * 1024 + n0 + bc4);
    __syncthreads();  // previous iteration's LDS reads done
    As[ak4 + 0][ar] = a1.x; As[ak4 + 1][ar] = a1.y;
    As[ak4 + 2][ar] = a1.z; As[ak4 + 3][ar] = a1.w;
    As[ak4 + 0][ar + 32] = a2.x; As[ak4 + 1][ar + 32] = a2.y;
    As[ak4 + 2][ar + 32] = a2.z; As[ak4 + 3][ar + 32] = a2.w;
    *(float4*)&Bs[bro][bc4] = b1;
    *(float4*)&Bs[bro + 16][bc4] = b2;
    __syncthreads();
#pragma unroll
    for (int kk = 0; kk < 32; ++kk) {
      const float4 av = *(const float4*)&As[kk][r0];
      const float4 bv = *(const float4*)&Bs[kk][c0];
      acc[0][0] += av.x * bv.x; acc[0][1] += av.x * bv.y; acc[0][2] += av.x * bv.z; acc[0][3] += av.x * bv.w;
      acc[1][0] += av.y * bv.x; acc[1][1] += av.y * bv.y; acc[1][2] += av.y * bv.z; acc[1][3] += av.y * bv.w;
      acc[2][0] += av.z * bv.x; acc[2][1] += av.z * bv.y; acc[2][2] += av.z * bv.z; acc[2][3] += av.z * bv.w;
      acc[3][0] += av.w * bv.x; acc[3][1] += av.w * bv.y; acc[3][2] += av.w * bv.z; acc[3][3] += av.w * bv.w;
    }
  }
  float* P = part + (size_t)bk * 262144;
#pragma unroll
  for (int i = 0; i < 4; ++i) {
    const float4 st = make_float4(acc[i][0], acc[i][1], acc[i][2], acc[i][3]);
    *(float4*)(P + (size_t)(m0 + r0 + i) * 1024 + n0 + c0) = st;
  }
}

// ---------------- K7c: reduce split-K partials ------------------------------
__global__ __launch_bounds__(256) void k7c_reduce(
    const float* __restrict__ part, float* __restrict__ hfc)
{
  const int idx = blockIdx.x * 256 + threadIdx.x;  // 262144 total
  float s = 0.f;
#pragma unroll
  for (int p = 0; p < 16; ++p) s += part[(size_t)p * 262144 + idx];
  hfc[idx] = s;
}

// ---------------- K8: bias+relu fused into fc2 ------------------------------
__global__ __launch_bounds__(256) void k8_fc2(
    const float* __restrict__ hfc, const float* __restrict__ fc1b,
    const float* __restrict__ w2, const float* __restrict__ b2,
    float* __restrict__ out)
{
  const int b = blockIdx.x, t = threadIdx.x;
  float acc[10];
#pragma unroll
  for (int o = 0; o < 10; ++o) acc[o] = 0.f;
  for (int jj = t; jj < 1024; jj += 256) {
    const float a = fmaxf(hfc[(size_t)b * 1024 + jj] + fc1b[jj], 0.f);
    const float* wr = w2 + (size_t)jj * 10;
#pragma unroll
    for (int o = 0; o < 10; ++o) acc[o] += a * wr[o];
  }
  __shared__ float red[256][10];
#pragma unroll
  for (int o = 0; o < 10; ++o) red[t][o] = acc[o];
  __syncthreads();
  for (int s = 128; s > 0; s >>= 1) {
    if (t < s) {
#pragma unroll
      for (int o = 0; o < 10; ++o) red[t][o] += red[t + s][o];
    }
    __syncthreads();
  }
  if (t < 10) out[b * 10 + t] = red[0][t] + b2[t];
}

// ---------------------------------------------------------------------------
extern "C" void kernel_launch(void* const* d_in, const int* in_sizes, int n_in,
                              void* d_out, int out_size, void* d_ws, size_t ws_size,
                              hipStream_t stream)
{
  const float* x    = (const float*)d_in[0];
  const float* w1c  = (const float*)d_in[1];
  const float* b1c  = (const float*)d_in[2];
  const float* w1q  = (const float*)d_in[3];
  const float* w1k  = (const float*)d_in[4];
  const float* w1v  = (const float*)d_in[5];
  const float* w1o  = (const float*)d_in[6];
  const float* b1o  = (const float*)d_in[7];
  const float* w2c  = (const float*)d_in[8];
  const float* b2c  = (const float*)d_in[9];
  const float* w2q  = (const float*)d_in[10];
  const float* w2k  = (const float*)d_in[11];
  const float* w2v  = (const float*)d_in[12];
  const float* w2o  = (const float*)d_in[13];
  const float* b2o  = (const float*)d_in[14];
  const float* fc1w = (const float*)d_in[15];
  const float* fc1b = (const float*)d_in[16];
  const float* fc2w = (const float*)d_in[17];
  const float* fc2b = (const float*)d_in[18];
  float* out = (float*)d_out;
  float* ws = (float*)d_ws;

  float* q1   = ws + OQ1;
  float* k1   = ws + OK1;
  float* v1   = ws + OV1;
  float* loc1 = ws + OL1;
  float* agg1 = ws + OA1;
  float* t2   = ws + OT2;
  float* q2   = ws + OQ2;
  float* k2   = ws + OK2;
  float* v2   = ws + OV2;
  float* loc2 = ws + OL2;
  float* agg2 = ws + OA2;
  float* h    = ws + OH;
  float* prt  = ws + OPART;
  float* hfc  = ws + OHFC;

  k1_qkv1<<<16384, 256, 0, stream>>>(x, w1q, w1k, w1v, w1c, b1c, q1, k1, v1, loc1);
  attn_kernel<16, 4><<<65536, 256, 0, stream>>>(q1, k1, v1, agg1);
  k3_out1<<<16384, 256, 0, stream>>>(loc1, agg1, w1o, b1o, t2);
  k4_qkv2<<<32768, 256, 0, stream>>>(t2, w2q, w2k, w2v, w2c, b2c, q2, k2, v2, loc2);
  attn_kernel<32, 8><<<65536, 256, 0, stream>>>(q2, k2, v2, agg2);
  k6_out2<<<32768, 256, 0, stream>>>(loc2, agg2, w2o, b2o, h);
  k7_fc1_gemm<<<1024, 256, 0, stream>>>(h, fc1w, prt);
  k7c_reduce<<<1024, 256, 0, stream>>>(prt, hfc);
  k8_fc2<<<256, 256, 0, stream>>>(hfc, fc1b, fc2w, fc2b, out);
}